// Round 2
// baseline (236.773 us; speedup 1.0000x reference)
//
#include <hip/hip_runtime.h>
#include <hip/hip_bf16.h>

#define Bn   32
#define HWn  676
#define Cn   768
#define Mn   32
#define NC   200
#define KT   (Mn*Cn)      // 24576
#define Sn   16
#define CHUNK 43          // ceil(676/16); last chunk = 31

#define LOGITS_OFF 0
#define ATTN_OFF   (Bn*NC)                 // 6400
#define EMB_OFF    (ATTN_OFF + Bn*HWn*Mn)  // 698624

// ---------------- zero init (logits, norm accum, optional part/emb) ----------
__global__ __launch_bounds__(256) void z_kernel(float* __restrict__ out,
                                                float* __restrict__ norm_acc,
                                                float* __restrict__ part,
                                                int part_elems, int zero_emb) {
    int gid = blockIdx.x * 256 + threadIdx.x;
    int stride = gridDim.x * 256;
    for (int i = gid; i < Bn * NC; i += stride) out[LOGITS_OFF + i] = 0.f;
    for (int i = gid; i < Bn; i += stride) norm_acc[i] = 0.f;
    for (int i = gid; i < part_elems; i += stride) part[i] = 0.f;
    if (zero_emb)
        for (int i = gid; i < Bn * KT; i += stride) out[EMB_OFF + i] = 0.f;
}

// ---------------- fused: attention maps + split-K bilinear pooling -----------
// grid = B*Sn = 512 blocks (2 per CU), 768 threads, ~6KB LDS.
__global__ __launch_bounds__(768, 6) void f_kernel(const float* __restrict__ f6,
                                                   const float* __restrict__ f7,
                                                   const float* __restrict__ wA,
                                                   float* __restrict__ attn_out,
                                                   float* __restrict__ part,
                                                   float* __restrict__ emb_atomic,
                                                   int mode) {
    __shared__ float attnS[CHUNK * Mn + 32];

    const int tid = threadIdx.x;
    const int b = blockIdx.x >> 4;
    const int s = blockIdx.x & 15;
    const int p0 = s * CHUNK;
    const int np = min(HWn - p0, CHUNK);

    // ---- phase 1: attention rows. thread = (position-slot, 2 m's) ----
    const int mg = tid & 15;  // m-pair: m = mg*2, mg*2+1
    const int pg = tid >> 4;  // 0..47 position slots
    if (pg < np) {
        const int p = p0 + pg;
        const float4* x4p = reinterpret_cast<const float4*>(f7 + ((size_t)b * HWn + p) * Cn);
        float a0 = 0.f, a1 = 0.f;
        #pragma unroll 4
        for (int c4 = 0; c4 < Cn / 4; ++c4) {
            float4 x = x4p[c4];
            const float* wb = wA + (size_t)c4 * 4 * Mn + mg * 2;  // L2-broadcast
            float2 w0 = *reinterpret_cast<const float2*>(wb);
            float2 w1 = *reinterpret_cast<const float2*>(wb + Mn);
            float2 w2 = *reinterpret_cast<const float2*>(wb + 2 * Mn);
            float2 w3 = *reinterpret_cast<const float2*>(wb + 3 * Mn);
            a0 += x.x * w0.x + x.y * w1.x + x.z * w2.x + x.w * w3.x;
            a1 += x.x * w0.y + x.y * w1.y + x.z * w2.y + x.w * w3.y;
        }
        float2 r; r.x = a0; r.y = a1;
        *reinterpret_cast<float2*>(&attnS[pg * Mn + mg * 2]) = r;
        *reinterpret_cast<float2*>(attn_out + ((size_t)(b * HWn + p)) * Mn + mg * 2) = r;
    }
    __syncthreads();

    // ---- phase 2: bilinear pooling partial, thread = one channel c ----
    float acc[Mn];
    #pragma unroll
    for (int m = 0; m < Mn; ++m) acc[m] = 0.f;

    const float* f6b = f6 + ((size_t)b * HWn + p0) * Cn + tid;
    for (int pl = 0; pl < np; ++pl) {
        float x = f6b[(size_t)pl * Cn];  // coalesced across the 768 threads
        const float4* ar = reinterpret_cast<const float4*>(&attnS[pl * Mn]); // broadcast
        #pragma unroll
        for (int mq = 0; mq < 8; ++mq) {
            float4 a = ar[mq];
            acc[4 * mq + 0] += a.x * x;
            acc[4 * mq + 1] += a.y * x;
            acc[4 * mq + 2] += a.z * x;
            acc[4 * mq + 3] += a.w * x;
        }
    }

    if (mode == 2) {
        float* pdst = part + ((size_t)(b * Sn + s)) * KT + tid;
        #pragma unroll
        for (int m = 0; m < Mn; ++m) pdst[m * Cn] = acc[m];
    } else if (mode == 1) {
        float* pdst = part + ((size_t)(b * 8 + (s & 7))) * KT + tid;
        #pragma unroll
        for (int m = 0; m < Mn; ++m) atomicAdd(pdst + m * Cn, acc[m]);
    } else {
        float* edst = emb_atomic + (size_t)b * KT + tid;
        #pragma unroll
        for (int m = 0; m < Mn; ++m) atomicAdd(edst + m * Cn, acc[m]);
    }
}

// ---------------- reduce split-K, signed sqrt, norm partial ------------------
// grid = B*8 = 256 blocks, 256 threads, float4 path. block = (b, eighth of KT)
__global__ __launch_bounds__(256) void r_kernel(const float* __restrict__ part,
                                                float* __restrict__ emb,
                                                float* __restrict__ norm_acc,
                                                int mode) {
    const int tid = threadIdx.x;
    const int b = blockIdx.x >> 3;
    const int g = blockIdx.x & 7;
    const int nslots = (mode == 2) ? Sn : 8;
    float lsq = 0.f;
    #pragma unroll
    for (int it = 0; it < 3; ++it) {
        size_t e = (size_t)g * 3072 + it * 1024 + tid * 4;
        float sx = 0.f, sy = 0.f, sz = 0.f, sw = 0.f;
        if (mode) {
            for (int s2 = 0; s2 < nslots; ++s2) {
                float4 p4 = *reinterpret_cast<const float4*>(
                    part + ((size_t)(b * nslots + s2)) * KT + e);
                sx += p4.x; sy += p4.y; sz += p4.z; sw += p4.w;
            }
        } else {
            float4 p4 = *reinterpret_cast<const float4*>(emb + (size_t)b * KT + e);
            sx = p4.x; sy = p4.y; sz = p4.z; sw = p4.w;
        }
        const float inv = 1.0f / (float)HWn;
        float4 o;
        o.x = copysignf(sqrtf(fabsf(sx * inv) + 1e-12f), sx);
        o.y = copysignf(sqrtf(fabsf(sy * inv) + 1e-12f), sy);
        o.z = copysignf(sqrtf(fabsf(sz * inv) + 1e-12f), sz);
        o.w = copysignf(sqrtf(fabsf(sw * inv) + 1e-12f), sw);
        *reinterpret_cast<float4*>(emb + (size_t)b * KT + e) = o;
        lsq += o.x * o.x + o.y * o.y + o.z * o.z + o.w * o.w;
    }
    #pragma unroll
    for (int o = 32; o > 0; o >>= 1) lsq += __shfl_down(lsq, o, 64);
    __shared__ float rb[4];
    if ((tid & 63) == 0) rb[tid >> 6] = lsq;
    __syncthreads();
    if (tid == 0) atomicAdd(&norm_acc[b], rb[0] + rb[1] + rb[2] + rb[3]);
}

// ---------------- normalize embeddings ---------------------------------------
__global__ __launch_bounds__(256) void n_kernel(float* __restrict__ emb,
                                                const float* __restrict__ norm_acc) {
    const int b = blockIdx.x >> 3;
    const int g = blockIdx.x & 7;
    float scale = rsqrtf(fmaxf(norm_acc[b], 1e-12f));
    float* p = emb + (size_t)b * KT + (size_t)g * 3072 + threadIdx.x * 4;
    #pragma unroll
    for (int it = 0; it < 3; ++it) {
        float4 v = *reinterpret_cast<float4*>(p + it * 1024);
        v.x *= scale; v.y *= scale; v.z *= scale; v.w *= scale;
        *reinterpret_cast<float4*>(p + it * 1024) = v;
    }
}

// ---------------- classifier: k-split, all 32 batches per block ---------------
// grid = KT/96 = 256 blocks, 256 threads. thread = one class n (<200).
__global__ __launch_bounds__(256) void l_kernel(const float* __restrict__ emb,
                                                const float* __restrict__ wC,
                                                float* __restrict__ logits) {
    __shared__ float eS[Bn * 96];  // 12 KB: emb chunk *100 for all 32 batches
    const int tid = threadIdx.x;
    const int k0 = blockIdx.x * 96;
    for (int i = tid; i < Bn * 96; i += 256) {
        int b = i / 96;
        int k = i - b * 96;
        eS[i] = emb[(size_t)b * KT + k0 + k] * 100.0f;
    }
    __syncthreads();
    if (tid < NC) {
        float acc[Bn];
        #pragma unroll
        for (int b = 0; b < Bn; ++b) acc[b] = 0.f;
        for (int kk = 0; kk < 96; ++kk) {
            float w = wC[(size_t)(k0 + kk) * NC + tid];  // coalesced across n
            #pragma unroll
            for (int b = 0; b < Bn; ++b) acc[b] += eS[b * 96 + kk] * w;  // LDS broadcast
        }
        #pragma unroll
        for (int b = 0; b < Bn; ++b) atomicAdd(&logits[b * NC + tid], acc[b]);
    }
}

extern "C" void kernel_launch(void* const* d_in, const int* in_sizes, int n_in,
                              void* d_out, int out_size, void* d_ws, size_t ws_size,
                              hipStream_t stream) {
    const float* f6 = (const float*)d_in[0];
    const float* f7 = (const float*)d_in[1];
    const float* wA = (const float*)d_in[2];
    const float* wC = (const float*)d_in[3];
    float* out = (float*)d_out;
    float* logits = out + LOGITS_OFF;
    float* attn = out + ATTN_OFF;
    float* emb = out + EMB_OFF;

    float* norm_acc = (float*)d_ws;                 // 32 floats
    float* part = (float*)((char*)d_ws + 128);      // partial buffer

    size_t need2 = 128 + (size_t)Bn * Sn * KT * sizeof(float);  // ~50 MB
    size_t need1 = 128 + (size_t)Bn * 8 * KT * sizeof(float);   // ~25 MB
    int mode = (ws_size >= need2) ? 2 : ((ws_size >= need1) ? 1 : 0);
    int part_elems = (mode == 1) ? Bn * 8 * KT : 0;

    z_kernel<<<1024, 256, 0, stream>>>(out, norm_acc, part, part_elems, mode == 0);
    f_kernel<<<Bn * Sn, 768, 0, stream>>>(f6, f7, wA, attn, part, emb, mode);
    r_kernel<<<Bn * 8, 256, 0, stream>>>(part, emb, norm_acc, mode);
    n_kernel<<<Bn * 8, 256, 0, stream>>>(emb, norm_acc);
    l_kernel<<<KT / 96, 256, 0, stream>>>(emb, wC, logits);
}

// Round 3
// 146.101 us; speedup vs baseline: 1.6206x; 1.6206x over previous
//
#include <hip/hip_runtime.h>
#include <hip/hip_bf16.h>

#define Bn   32
#define HWn  676
#define Cn   768
#define Mn   32
#define NC   200
#define KT   (Mn*Cn)      // 24576

#define PB   11           // 64-position tiles per batch (a_kernel)
#define TP   64
#define KS   64           // k-slice
#define XPAD 68           // 272B row stride: 16B-aligned, conflict-free

#define SnB  16           // position chunks per batch (b_kernel)
#define CHB  43           // ceil(676/16); last = 31

#define LOGITS_OFF 0
#define ATTN_OFF   (Bn*NC)                 // 6400
#define EMB_OFF    (ATTN_OFF + Bn*HWn*Mn)  // 698624

// ---------------- zero init: logits, norm accum, emb -------------------------
__global__ __launch_bounds__(256) void z_kernel(float* __restrict__ out,
                                                float* __restrict__ norm_acc) {
    int gid = blockIdx.x * 256 + threadIdx.x;
    int stride = gridDim.x * 256;
    for (int i = gid; i < Bn * NC; i += stride) out[LOGITS_OFF + i] = 0.f;
    for (int i = gid; i < Bn; i += stride) norm_acc[i] = 0.f;
    for (int i = gid; i < Bn * KT; i += stride) out[EMB_OFF + i] = 0.f;
}

// ---------------- a: attention GEMM (B*HW,768) x (768,32) --------------------
// grid = Bn*PB = 352 blocks, 256 threads. Tile: 64 pos x 32 m, K sliced by 64.
__global__ __launch_bounds__(256) void a_kernel(const float* __restrict__ f7,
                                                const float* __restrict__ wA,
                                                float* __restrict__ attn_out) {
    __shared__ float xs[TP][XPAD];   // 17408 B
    __shared__ float wsf[KS * Mn];   // 8192 B
    const int tid = threadIdx.x;
    const int b  = blockIdx.x / PB;
    const int t  = blockIdx.x % PB;
    const int p0 = t * TP;
    const int pg = tid >> 3;   // 0..31 (positions pg and pg+32)
    const int mg = tid & 7;    // m quad: mg*4..mg*4+3

    float4 acc0 = {0.f, 0.f, 0.f, 0.f};
    float4 acc1 = {0.f, 0.f, 0.f, 0.f};

    for (int ks = 0; ks < Cn / KS; ++ks) {
        const int c0 = ks * KS;
        // stage f7 tile: 64 rows x 64 c, coalesced 256B row segments
        #pragma unroll
        for (int r = 0; r < 4; ++r) {
            int f = tid + r * 256;          // float4 index 0..1023
            int p = f >> 4, c4 = f & 15;
            int prow = p0 + p; if (prow > HWn - 1) prow = HWn - 1;  // clamp tail
            float4 v = *reinterpret_cast<const float4*>(
                f7 + ((size_t)b * HWn + prow) * Cn + c0 + c4 * 4);
            *reinterpret_cast<float4*>(&xs[p][c4 * 4]) = v;
        }
        // stage wA slice: 64 x 32, contiguous
        #pragma unroll
        for (int r = 0; r < 2; ++r) {
            int f = tid + r * 256;          // float4 index 0..511
            *reinterpret_cast<float4*>(&wsf[f * 4]) =
                *reinterpret_cast<const float4*>(wA + (size_t)c0 * Mn + f * 4);
        }
        __syncthreads();
        #pragma unroll
        for (int k4 = 0; k4 < KS / 4; ++k4) {
            float4 x0 = *reinterpret_cast<const float4*>(&xs[pg][k4 * 4]);
            float4 x1 = *reinterpret_cast<const float4*>(&xs[pg + 32][k4 * 4]);
            float4 w0 = *reinterpret_cast<const float4*>(&wsf[(k4 * 4 + 0) * Mn + mg * 4]);
            float4 w1 = *reinterpret_cast<const float4*>(&wsf[(k4 * 4 + 1) * Mn + mg * 4]);
            float4 w2 = *reinterpret_cast<const float4*>(&wsf[(k4 * 4 + 2) * Mn + mg * 4]);
            float4 w3 = *reinterpret_cast<const float4*>(&wsf[(k4 * 4 + 3) * Mn + mg * 4]);
            acc0.x += x0.x*w0.x + x0.y*w1.x + x0.z*w2.x + x0.w*w3.x;
            acc0.y += x0.x*w0.y + x0.y*w1.y + x0.z*w2.y + x0.w*w3.y;
            acc0.z += x0.x*w0.z + x0.y*w1.z + x0.z*w2.z + x0.w*w3.z;
            acc0.w += x0.x*w0.w + x0.y*w1.w + x0.z*w2.w + x0.w*w3.w;
            acc1.x += x1.x*w0.x + x1.y*w1.x + x1.z*w2.x + x1.w*w3.x;
            acc1.y += x1.x*w0.y + x1.y*w1.y + x1.z*w2.y + x1.w*w3.y;
            acc1.z += x1.x*w0.z + x1.y*w1.z + x1.z*w2.z + x1.w*w3.z;
            acc1.w += x1.x*w0.w + x1.y*w1.w + x1.z*w2.w + x1.w*w3.w;
        }
        __syncthreads();
    }
    int prow0 = p0 + pg;
    if (prow0 < HWn)
        *reinterpret_cast<float4*>(attn_out + ((size_t)b * HWn + prow0) * Mn + mg * 4) = acc0;
    int prow1 = p0 + pg + 32;
    if (prow1 < HWn)
        *reinterpret_cast<float4*>(attn_out + ((size_t)b * HWn + prow1) * Mn + mg * 4) = acc1;
}

// ---------------- b: bilinear pooling, split-K atomics into emb --------------
// grid = Bn*SnB = 512 blocks, 768 threads (thread = channel). No LDS.
__global__ __launch_bounds__(768, 6) void b_kernel(const float* __restrict__ f6,
                                                   const float* __restrict__ attn,
                                                   float* __restrict__ emb) {
    const int tid = threadIdx.x;
    const int b = blockIdx.x >> 4;
    const int s = blockIdx.x & 15;
    const int p0 = s * CHB;
    const int np = min(HWn - p0, CHB);

    float acc[Mn];
    #pragma unroll
    for (int m = 0; m < Mn; ++m) acc[m] = 0.f;

    const float* arow = attn + ((size_t)b * HWn + p0) * Mn;
    const float* xcol = f6 + ((size_t)b * HWn + p0) * Cn + tid;
    for (int pl = 0; pl < np; ++pl) {
        float x = xcol[(size_t)pl * Cn];                       // coalesced
        const float4* ar = reinterpret_cast<const float4*>(arow + pl * Mn); // uniform
        {
            float4 a0 = ar[0], a1 = ar[1], a2 = ar[2], a3 = ar[3];
            acc[0]  += a0.x * x;  acc[1]  += a0.y * x;  acc[2]  += a0.z * x;  acc[3]  += a0.w * x;
            acc[4]  += a1.x * x;  acc[5]  += a1.y * x;  acc[6]  += a1.z * x;  acc[7]  += a1.w * x;
            acc[8]  += a2.x * x;  acc[9]  += a2.y * x;  acc[10] += a2.z * x;  acc[11] += a2.w * x;
            acc[12] += a3.x * x;  acc[13] += a3.y * x;  acc[14] += a3.z * x;  acc[15] += a3.w * x;
        }
        {
            float4 a4 = ar[4], a5 = ar[5], a6 = ar[6], a7 = ar[7];
            acc[16] += a4.x * x;  acc[17] += a4.y * x;  acc[18] += a4.z * x;  acc[19] += a4.w * x;
            acc[20] += a5.x * x;  acc[21] += a5.y * x;  acc[22] += a5.z * x;  acc[23] += a5.w * x;
            acc[24] += a6.x * x;  acc[25] += a6.y * x;  acc[26] += a6.z * x;  acc[27] += a6.w * x;
            acc[28] += a7.x * x;  acc[29] += a7.y * x;  acc[30] += a7.z * x;  acc[31] += a7.w * x;
        }
    }

    float* edst = emb + (size_t)b * KT + tid;
    #pragma unroll
    for (int m = 0; m < Mn; ++m) atomicAdd(edst + (size_t)m * Cn, acc[m]);
}

// ---------------- r: /HW, signed sqrt, norm partial (in-place on emb) --------
__global__ __launch_bounds__(256) void r_kernel(float* __restrict__ emb,
                                                float* __restrict__ norm_acc) {
    const int tid = threadIdx.x;
    const int b = blockIdx.x >> 3;
    const int g = blockIdx.x & 7;
    const float inv = 1.0f / (float)HWn;
    float lsq = 0.f;
    #pragma unroll
    for (int it = 0; it < 3; ++it) {
        size_t e = (size_t)b * KT + (size_t)g * 3072 + it * 1024 + tid * 4;
        float4 v = *reinterpret_cast<float4*>(emb + e);
        float4 o;
        o.x = copysignf(sqrtf(fabsf(v.x * inv) + 1e-12f), v.x);
        o.y = copysignf(sqrtf(fabsf(v.y * inv) + 1e-12f), v.y);
        o.z = copysignf(sqrtf(fabsf(v.z * inv) + 1e-12f), v.z);
        o.w = copysignf(sqrtf(fabsf(v.w * inv) + 1e-12f), v.w);
        *reinterpret_cast<float4*>(emb + e) = o;
        lsq += o.x * o.x + o.y * o.y + o.z * o.z + o.w * o.w;
    }
    #pragma unroll
    for (int o = 32; o > 0; o >>= 1) lsq += __shfl_down(lsq, o, 64);
    __shared__ float rb[4];
    if ((tid & 63) == 0) rb[tid >> 6] = lsq;
    __syncthreads();
    if (tid == 0) atomicAdd(&norm_acc[b], rb[0] + rb[1] + rb[2] + rb[3]);
}

// ---------------- n: scale by rsqrt(norm) ------------------------------------
__global__ __launch_bounds__(256) void n_kernel(float* __restrict__ emb,
                                                const float* __restrict__ norm_acc) {
    const int b = blockIdx.x >> 3;
    const int g = blockIdx.x & 7;
    float scale = rsqrtf(fmaxf(norm_acc[b], 1e-12f));
    float* p = emb + (size_t)b * KT + (size_t)g * 3072 + threadIdx.x * 4;
    #pragma unroll
    for (int it = 0; it < 3; ++it) {
        float4 v = *reinterpret_cast<float4*>(p + it * 1024);
        v.x *= scale; v.y *= scale; v.z *= scale; v.w *= scale;
        *reinterpret_cast<float4*>(p + it * 1024) = v;
    }
}

// ---------------- l: classifier, k-split -------------------------------------
__global__ __launch_bounds__(256) void l_kernel(const float* __restrict__ emb,
                                                const float* __restrict__ wC,
                                                float* __restrict__ logits) {
    __shared__ float eS[Bn * 96];
    const int tid = threadIdx.x;
    const int k0 = blockIdx.x * 96;
    for (int i = tid; i < Bn * 96; i += 256) {
        int b = i / 96;
        int k = i - b * 96;
        eS[i] = emb[(size_t)b * KT + k0 + k] * 100.0f;
    }
    __syncthreads();
    if (tid < NC) {
        float acc[Bn];
        #pragma unroll
        for (int b = 0; b < Bn; ++b) acc[b] = 0.f;
        for (int kk = 0; kk < 96; ++kk) {
            float w = wC[(size_t)(k0 + kk) * NC + tid];
            #pragma unroll
            for (int b = 0; b < Bn; ++b) acc[b] += eS[b * 96 + kk] * w;
        }
        #pragma unroll
        for (int b = 0; b < Bn; ++b) atomicAdd(&logits[b * NC + tid], acc[b]);
    }
}

extern "C" void kernel_launch(void* const* d_in, const int* in_sizes, int n_in,
                              void* d_out, int out_size, void* d_ws, size_t ws_size,
                              hipStream_t stream) {
    const float* f6 = (const float*)d_in[0];
    const float* f7 = (const float*)d_in[1];
    const float* wA = (const float*)d_in[2];
    const float* wC = (const float*)d_in[3];
    float* out = (float*)d_out;
    float* logits = out + LOGITS_OFF;
    float* attn = out + ATTN_OFF;
    float* emb = out + EMB_OFF;
    float* norm_acc = (float*)d_ws;   // 32 floats

    z_kernel<<<1024, 256, 0, stream>>>(out, norm_acc);
    a_kernel<<<Bn * PB, 256, 0, stream>>>(f7, wA, attn);
    b_kernel<<<Bn * SnB, 768, 0, stream>>>(f6, attn, emb);
    r_kernel<<<Bn * 8, 256, 0, stream>>>(emb, norm_acc);
    n_kernel<<<Bn * 8, 256, 0, stream>>>(emb, norm_acc);
    l_kernel<<<KT / 96, 256, 0, stream>>>(emb, wC, logits);
}

// Round 4
// 140.336 us; speedup vs baseline: 1.6872x; 1.0411x over previous
//
#include <hip/hip_runtime.h>
#include <hip/hip_bf16.h>

#define Bn   32
#define HWn  676
#define Cn   768
#define Mn   32
#define NC   200
#define KT   (Mn*Cn)      // 24576

// a_kernel tiling
#define TPa  64           // positions per tile
#define PBa  11           // tiles per batch
#define KSa  64           // k-slice per stage
#define KH   384          // k per split-half
#define NSL  (KH/KSa)     // 6 slices
#define XPAD 68           // 272B row stride, 16B aligned, <=2-way banks

// b_kernel chunking
#define SnB  16
#define CHB  43           // ceil(676/16); last = 31

#define LOGITS_OFF 0
#define ATTN_OFF   (Bn*NC)                 // 6400
#define EMB_OFF    (ATTN_OFF + Bn*HWn*Mn)  // 698624

// ---------------- z: zero logits, norm accum, emb ----------------------------
__global__ __launch_bounds__(256) void z_kernel(float* __restrict__ out,
                                                float* __restrict__ norm_acc) {
    int gid = blockIdx.x * 256 + threadIdx.x;
    int stride = gridDim.x * 256;
    for (int i = gid; i < Bn * NC; i += stride) out[LOGITS_OFF + i] = 0.f;
    for (int i = gid; i < Bn; i += stride) norm_acc[i] = 0.f;
    for (int i = gid; i < Bn * KT; i += stride) out[EMB_OFF + i] = 0.f;
}

// ---------------- a: attention GEMM, K-split x2, double-buffered LDS ---------
// grid = Bn*PBa*2 = 704 blocks, 512 threads. Tile 64 pos x 32 m, K-half 384.
__global__ __launch_bounds__(512, 6) void a_kernel(const float* __restrict__ f7,
                                                   const float* __restrict__ wA,
                                                   float* __restrict__ part) {
    __shared__ float xs[2][TPa][XPAD];   // 34816 B
    __shared__ float wsf[2][KSa * Mn];   // 16384 B
    const int tid = threadIdx.x;
    const int b   = blockIdx.x / (PBa * 2);
    const int rem = blockIdx.x % (PBa * 2);
    const int t   = rem >> 1;
    const int h   = rem & 1;
    const int p0  = t * TPa;
    const int cb  = h * KH;

    float4 xr0, xr1, wr;

#define A_LOAD(ks) do {                                                        \
    int c0_ = cb + (ks) * KSa;                                                 \
    int p_0 = tid >> 4, c40 = tid & 15;                                        \
    int pr0 = p0 + p_0; if (pr0 > HWn - 1) pr0 = HWn - 1;                      \
    xr0 = *reinterpret_cast<const float4*>(                                    \
        f7 + ((size_t)b * HWn + pr0) * Cn + c0_ + c40 * 4);                    \
    int f1 = tid + 512;                                                        \
    int p_1 = f1 >> 4, c41 = f1 & 15;                                          \
    int pr1 = p0 + p_1; if (pr1 > HWn - 1) pr1 = HWn - 1;                      \
    xr1 = *reinterpret_cast<const float4*>(                                    \
        f7 + ((size_t)b * HWn + pr1) * Cn + c0_ + c41 * 4);                    \
    wr = *reinterpret_cast<const float4*>(wA + (size_t)c0_ * Mn + tid * 4);    \
} while (0)

#define A_WRITE(bufw) do {                                                     \
    int p_0 = tid >> 4, c40 = tid & 15;                                        \
    *reinterpret_cast<float4*>(&xs[bufw][p_0][c40 * 4]) = xr0;                 \
    int f1 = tid + 512;                                                        \
    int p_1 = f1 >> 4, c41 = f1 & 15;                                          \
    *reinterpret_cast<float4*>(&xs[bufw][p_1][c41 * 4]) = xr1;                 \
    *reinterpret_cast<float4*>(&wsf[bufw][tid * 4]) = wr;                      \
} while (0)

    A_LOAD(0);
    A_WRITE(0);

    const int pg = tid >> 3;   // 0..63 position
    const int mg = tid & 7;    // m quad
    float4 acc = {0.f, 0.f, 0.f, 0.f};
    int buf = 0;

    for (int ks = 0; ks < NSL; ++ks) {
        __syncthreads();
        if (ks < NSL - 1) A_LOAD(ks + 1);     // global->reg, latency hidden
        #pragma unroll
        for (int k4 = 0; k4 < KSa / 4; ++k4) {
            float4 x = *reinterpret_cast<const float4*>(&xs[buf][pg][k4 * 4]);
            const float* wb = &wsf[buf][(k4 * 4) * Mn + mg * 4];
            float4 w0 = *reinterpret_cast<const float4*>(wb);
            float4 w1 = *reinterpret_cast<const float4*>(wb + Mn);
            float4 w2 = *reinterpret_cast<const float4*>(wb + 2 * Mn);
            float4 w3 = *reinterpret_cast<const float4*>(wb + 3 * Mn);
            acc.x += x.x * w0.x + x.y * w1.x + x.z * w2.x + x.w * w3.x;
            acc.y += x.x * w0.y + x.y * w1.y + x.z * w2.y + x.w * w3.y;
            acc.z += x.x * w0.z + x.y * w1.z + x.z * w2.z + x.w * w3.z;
            acc.w += x.x * w0.w + x.y * w1.w + x.z * w2.w + x.w * w3.w;
        }
        if (ks < NSL - 1) A_WRITE(buf ^ 1);   // reg->LDS after compute
        buf ^= 1;
    }

    int pr = p0 + pg;
    if (pr < HWn)
        *reinterpret_cast<float4*>(
            part + ((size_t)(h * Bn + b) * HWn + pr) * Mn + mg * 4) = acc;
#undef A_LOAD
#undef A_WRITE
}

// ---------------- b: sum halves -> attn out + LDS; bilinear pooling ----------
// grid = Bn*SnB = 512 blocks, 768 threads (thread = channel).
__global__ __launch_bounds__(768, 6) void b_kernel(const float* __restrict__ f6,
                                                   const float* __restrict__ part,
                                                   float* __restrict__ attn_out,
                                                   float* __restrict__ emb) {
    __shared__ float attnS[CHB * Mn];   // 5504 B
    const int tid = threadIdx.x;
    const int b = blockIdx.x >> 4;
    const int s = blockIdx.x & 15;
    const int p0 = s * CHB;
    const int np = min(HWn - p0, CHB);
    const int ne = np * Mn;

    const size_t base0 = ((size_t)(0 * Bn + b) * HWn + p0) * Mn;
    const size_t base1 = ((size_t)(1 * Bn + b) * HWn + p0) * Mn;
    const size_t baseo = ((size_t)b * HWn + p0) * Mn;
    for (int i = tid; i < ne; i += 768) {
        float v = part[base0 + i] + part[base1 + i];
        attnS[i] = v;
        attn_out[baseo + i] = v;
    }
    __syncthreads();

    float4 a0 = {0,0,0,0}, a1 = {0,0,0,0}, a2 = {0,0,0,0}, a3 = {0,0,0,0};
    float4 a4 = {0,0,0,0}, a5 = {0,0,0,0}, a6 = {0,0,0,0}, a7 = {0,0,0,0};

    const float* xcol = f6 + ((size_t)b * HWn + p0) * Cn + tid;
    #pragma unroll 2
    for (int pl = 0; pl < np; ++pl) {
        float x = xcol[(size_t)pl * Cn];  // coalesced
        const float4* ar = reinterpret_cast<const float4*>(&attnS[pl * Mn]); // broadcast
        float4 t0 = ar[0], t1 = ar[1], t2 = ar[2], t3 = ar[3];
        float4 t4 = ar[4], t5 = ar[5], t6 = ar[6], t7 = ar[7];
        a0.x += t0.x * x; a0.y += t0.y * x; a0.z += t0.z * x; a0.w += t0.w * x;
        a1.x += t1.x * x; a1.y += t1.y * x; a1.z += t1.z * x; a1.w += t1.w * x;
        a2.x += t2.x * x; a2.y += t2.y * x; a2.z += t2.z * x; a2.w += t2.w * x;
        a3.x += t3.x * x; a3.y += t3.y * x; a3.z += t3.z * x; a3.w += t3.w * x;
        a4.x += t4.x * x; a4.y += t4.y * x; a4.z += t4.z * x; a4.w += t4.w * x;
        a5.x += t5.x * x; a5.y += t5.y * x; a5.z += t5.z * x; a5.w += t5.w * x;
        a6.x += t6.x * x; a6.y += t6.y * x; a6.z += t6.z * x; a6.w += t6.w * x;
        a7.x += t7.x * x; a7.y += t7.y * x; a7.z += t7.z * x; a7.w += t7.w * x;
    }

    float* e = emb + (size_t)b * KT + tid;
    atomicAdd(e + (size_t)0  * Cn, a0.x); atomicAdd(e + (size_t)1  * Cn, a0.y);
    atomicAdd(e + (size_t)2  * Cn, a0.z); atomicAdd(e + (size_t)3  * Cn, a0.w);
    atomicAdd(e + (size_t)4  * Cn, a1.x); atomicAdd(e + (size_t)5  * Cn, a1.y);
    atomicAdd(e + (size_t)6  * Cn, a1.z); atomicAdd(e + (size_t)7  * Cn, a1.w);
    atomicAdd(e + (size_t)8  * Cn, a2.x); atomicAdd(e + (size_t)9  * Cn, a2.y);
    atomicAdd(e + (size_t)10 * Cn, a2.z); atomicAdd(e + (size_t)11 * Cn, a2.w);
    atomicAdd(e + (size_t)12 * Cn, a3.x); atomicAdd(e + (size_t)13 * Cn, a3.y);
    atomicAdd(e + (size_t)14 * Cn, a3.z); atomicAdd(e + (size_t)15 * Cn, a3.w);
    atomicAdd(e + (size_t)16 * Cn, a4.x); atomicAdd(e + (size_t)17 * Cn, a4.y);
    atomicAdd(e + (size_t)18 * Cn, a4.z); atomicAdd(e + (size_t)19 * Cn, a4.w);
    atomicAdd(e + (size_t)20 * Cn, a5.x); atomicAdd(e + (size_t)21 * Cn, a5.y);
    atomicAdd(e + (size_t)22 * Cn, a5.z); atomicAdd(e + (size_t)23 * Cn, a5.w);
    atomicAdd(e + (size_t)24 * Cn, a6.x); atomicAdd(e + (size_t)25 * Cn, a6.y);
    atomicAdd(e + (size_t)26 * Cn, a6.z); atomicAdd(e + (size_t)27 * Cn, a6.w);
    atomicAdd(e + (size_t)28 * Cn, a7.x); atomicAdd(e + (size_t)29 * Cn, a7.y);
    atomicAdd(e + (size_t)30 * Cn, a7.z); atomicAdd(e + (size_t)31 * Cn, a7.w);
}

// ---------------- r: /HW, signed sqrt, norm partial (in-place on emb) --------
__global__ __launch_bounds__(256) void r_kernel(float* __restrict__ emb,
                                                float* __restrict__ norm_acc) {
    const int tid = threadIdx.x;
    const int b = blockIdx.x >> 3;
    const int g = blockIdx.x & 7;
    const float inv = 1.0f / (float)HWn;
    float lsq = 0.f;
    #pragma unroll
    for (int it = 0; it < 3; ++it) {
        size_t e = (size_t)b * KT + (size_t)g * 3072 + it * 1024 + tid * 4;
        float4 v = *reinterpret_cast<float4*>(emb + e);
        float4 o;
        o.x = copysignf(sqrtf(fabsf(v.x * inv) + 1e-12f), v.x);
        o.y = copysignf(sqrtf(fabsf(v.y * inv) + 1e-12f), v.y);
        o.z = copysignf(sqrtf(fabsf(v.z * inv) + 1e-12f), v.z);
        o.w = copysignf(sqrtf(fabsf(v.w * inv) + 1e-12f), v.w);
        *reinterpret_cast<float4*>(emb + e) = o;
        lsq += o.x * o.x + o.y * o.y + o.z * o.z + o.w * o.w;
    }
    #pragma unroll
    for (int o = 32; o > 0; o >>= 1) lsq += __shfl_down(lsq, o, 64);
    __shared__ float rb[4];
    if ((tid & 63) == 0) rb[tid >> 6] = lsq;
    __syncthreads();
    if (tid == 0) atomicAdd(&norm_acc[b], rb[0] + rb[1] + rb[2] + rb[3]);
}

// ---------------- l: normalize emb (write output) + classifier ---------------
// grid = KT/96 = 256 blocks, 256 threads.
__global__ __launch_bounds__(256) void l_kernel(float* __restrict__ emb,
                                                const float* __restrict__ wC,
                                                const float* __restrict__ norm_acc,
                                                float* __restrict__ logits) {
    __shared__ float eS[Bn * 96];
    __shared__ float sS[Bn];
    const int tid = threadIdx.x;
    if (tid < Bn) sS[tid] = rsqrtf(fmaxf(norm_acc[tid], 1e-12f));
    __syncthreads();
    const int k0 = blockIdx.x * 96;
    for (int i = tid; i < Bn * 96; i += 256) {
        int b = i / 96;
        int k = i - b * 96;
        float v = emb[(size_t)b * KT + k0 + k] * sS[b];
        emb[(size_t)b * KT + k0 + k] = v;   // normalized embeddings output
        eS[i] = v * 100.0f;                  // features for logits
    }
    __syncthreads();
    if (tid < NC) {
        float acc[Bn];
        #pragma unroll
        for (int b = 0; b < Bn; ++b) acc[b] = 0.f;
        for (int kk = 0; kk < 96; ++kk) {
            float w = wC[(size_t)(k0 + kk) * NC + tid];  // coalesced
            #pragma unroll
            for (int b = 0; b < Bn; ++b) acc[b] += eS[b * 96 + kk] * w;
        }
        #pragma unroll
        for (int b = 0; b < Bn; ++b) atomicAdd(&logits[b * NC + tid], acc[b]);
    }
}

extern "C" void kernel_launch(void* const* d_in, const int* in_sizes, int n_in,
                              void* d_out, int out_size, void* d_ws, size_t ws_size,
                              hipStream_t stream) {
    const float* f6 = (const float*)d_in[0];
    const float* f7 = (const float*)d_in[1];
    const float* wA = (const float*)d_in[2];
    const float* wC = (const float*)d_in[3];
    float* out = (float*)d_out;
    float* logits = out + LOGITS_OFF;
    float* attn = out + ATTN_OFF;
    float* emb = out + EMB_OFF;

    float* norm_acc = (float*)d_ws;                 // 32 floats
    float* part = (float*)((char*)d_ws + 128);      // 2 x B x HW x M f32 = 5.5 MB

    z_kernel<<<1024, 256, 0, stream>>>(out, norm_acc);
    a_kernel<<<Bn * PBa * 2, 512, 0, stream>>>(f7, wA, part);
    b_kernel<<<Bn * SnB, 768, 0, stream>>>(f6, part, attn, emb);
    r_kernel<<<Bn * 8, 256, 0, stream>>>(emb, norm_acc);
    l_kernel<<<KT / 96, 256, 0, stream>>>(emb, wC, norm_acc, logits);
}